// Round 7
// baseline (431.826 us; speedup 1.0000x reference)
//
#include <hip/hip_runtime.h>
#include <hip/hip_bf16.h>

#define B_ 512
#define E_ 1024
#define N_ 1024
#define M_ 128
#define P_ 134   // M+6

__device__ __forceinline__ float softplus_f(float x) {
    return fmaxf(x, 0.f) + log1pf(expf(-fabsf(x)));
}

// Fully fused NTM read head. One block per b, 512 threads (8 waves), ~18KB LDS
// -> 2 blocks/CU co-resident (single generation, phases of neighboring blocks
// overlap). Pass structure: 8 lanes per memory row (each lane owns 16
// consecutive floats); dot/|m| accumulate IN-LANE (32 indep FMAs / 4KB), only
// 6 shfl per 8 rows. Pass 2 re-reads memory from L2/L3 (proven resident:
// round-6 FETCH was 211MB < one pass) with per-lane float4 accumulators.
__global__ __launch_bounds__(512, 4) void k_fused(
    const float* __restrict__ emb, const float* __restrict__ W,
    const float* __restrict__ bias, const float* __restrict__ w_prev,
    const float* __restrict__ mem,
    float* __restrict__ out_md, float* __restrict__ out_w)
{
    __shared__ float se[E_];             // emb row
    __shared__ float partial[2][136];    // E-split partial dots
    __shared__ float sp[136];            // params row
    __shared__ float sscal[8];           // beta,g,s0,s1,s2,y,knorm
    __shared__ float zbuf[N_];           // z, later final w
    __shared__ float wgbuf[N_];          // gated weights
    __shared__ float red[8];
    __shared__ float accw[8][M_];        // per-wave pass-2 partials

    const int b    = blockIdx.x;
    const int t    = threadIdx.x;
    const int wid  = t >> 6;             // wave 0..7
    const int lane = t & 63;
    const int c    = lane & 7;           // 16-float chunk within row
    const int rg   = lane >> 3;          // row-group 0..7

    // ---- phase A: params = emb[b] @ W + bias (E split in halves) ----
    se[t] = emb[b * E_ + t];
    se[t + 512] = emb[b * E_ + t + 512];
    __syncthreads();
    if (t < 268) {
        const int seg = t / 134;
        const int col = t - seg * 134;
        const int e0 = seg * 512;
        const float* wcol = W + col;
        float a0 = 0.f, a1 = 0.f, a2 = 0.f, a3 = 0.f;
        #pragma unroll 4
        for (int e = 0; e < 512; e += 4) {
            a0 = fmaf(se[e0 + e + 0], wcol[(size_t)(e0 + e + 0) * P_], a0);
            a1 = fmaf(se[e0 + e + 1], wcol[(size_t)(e0 + e + 1) * P_], a1);
            a2 = fmaf(se[e0 + e + 2], wcol[(size_t)(e0 + e + 2) * P_], a2);
            a3 = fmaf(se[e0 + e + 3], wcol[(size_t)(e0 + e + 3) * P_], a3);
        }
        partial[seg][col] = (a0 + a1) + (a2 + a3);
    }
    __syncthreads();
    if (t < P_) sp[t] = bias[t] + partial[0][t] + partial[1][t];
    __syncthreads();
    if (t < 64) {                        // ||k||
        float v = sp[t] * sp[t] + sp[t + 64] * sp[t + 64];
        #pragma unroll
        for (int m = 1; m < 64; m <<= 1) v += __shfl_xor(v, m);
        if (t == 0) sscal[6] = sqrtf(v);
    }
    if (t == 64) {                       // scalar params (wave 1, overlaps)
        sscal[0] = softplus_f(sp[M_ + 0]);
        sscal[1] = 1.f / (1.f + expf(-sp[M_ + 1]));
        float a0 = sp[M_ + 2], a1 = sp[M_ + 3], a2 = sp[M_ + 4];
        float mx = fmaxf(a0, fmaxf(a1, a2));
        float e0 = expf(a0 - mx), e1 = expf(a1 - mx), e2 = expf(a2 - mx);
        float inv = 1.f / (e0 + e1 + e2);
        sscal[2] = e0 * inv; sscal[3] = e1 * inv; sscal[4] = e2 * inv;
        sscal[5] = 1.f + softplus_f(sp[M_ + 5]);
    }
    __syncthreads();

    const float kn   = sscal[6];
    const float beta = sscal[0];
    const float g    = sscal[1];
    const float s0   = sscal[2];
    const float s1   = sscal[3];
    const float s2   = sscal[4];
    const float y    = sscal[5];

    // per-lane k chunk: 16 floats
    const float4 kf0 = *(const float4*)&sp[c * 16 + 0];
    const float4 kf1 = *(const float4*)&sp[c * 16 + 4];
    const float4 kf2 = *(const float4*)&sp[c * 16 + 8];
    const float4 kf3 = *(const float4*)&sp[c * 16 + 12];

    // wave wid owns rows [wid*128, wid*128+128): 16 iters x 8 rows
    const float* rowbase = mem + ((size_t)b * N_ + wid * 128 + rg) * M_ + c * 16;

    // ---- pass 1: z[n] = beta * cos(k, mem[b,n]) ----
    #pragma unroll 4
    for (int i = 0; i < 16; ++i) {
        const float4* p = (const float4*)(rowbase + (size_t)i * 8 * M_);
        const float4 v0 = p[0], v1 = p[1], v2 = p[2], v3 = p[3];
        float dot = v0.x * kf0.x + v0.y * kf0.y + v0.z * kf0.z + v0.w * kf0.w;
        float sq  = v0.x * v0.x + v0.y * v0.y + v0.z * v0.z + v0.w * v0.w;
        dot += v1.x * kf1.x + v1.y * kf1.y + v1.z * kf1.z + v1.w * kf1.w;
        sq  += v1.x * v1.x + v1.y * v1.y + v1.z * v1.z + v1.w * v1.w;
        dot += v2.x * kf2.x + v2.y * kf2.y + v2.z * kf2.z + v2.w * kf2.w;
        sq  += v2.x * v2.x + v2.y * v2.y + v2.z * v2.z + v2.w * v2.w;
        dot += v3.x * kf3.x + v3.y * kf3.y + v3.z * kf3.z + v3.w * kf3.w;
        sq  += v3.x * v3.x + v3.y * v3.y + v3.z * v3.z + v3.w * v3.w;
        #pragma unroll
        for (int m = 1; m < 8; m <<= 1) {
            dot += __shfl_xor(dot, m);
            sq  += __shfl_xor(sq,  m);
        }
        if (c == 0)
            zbuf[wid * 128 + i * 8 + rg] = beta * dot / (kn * sqrtf(sq) + 1e-16f);
    }
    __syncthreads();

    // ---- phase B: softmax over N + gate + shift + pow + renorm (2 elems/thr)
    const float z0 = zbuf[t], z1 = zbuf[t + 512];
    float v = fmaxf(z0, z1);
    #pragma unroll
    for (int m = 1; m < 64; m <<= 1) v = fmaxf(v, __shfl_xor(v, m));
    if (lane == 0) red[wid] = v;
    __syncthreads();
    float mx = red[0];
    #pragma unroll
    for (int j = 1; j < 8; ++j) mx = fmaxf(mx, red[j]);
    const float e0 = expf(z0 - mx), e1 = expf(z1 - mx);
    v = e0 + e1;
    #pragma unroll
    for (int m = 1; m < 64; m <<= 1) v += __shfl_xor(v, m);
    __syncthreads();
    if (lane == 0) red[wid] = v;
    __syncthreads();
    float esum = 0.f;
    #pragma unroll
    for (int j = 0; j < 8; ++j) esum += red[j];
    const float einv = 1.f / esum;
    wgbuf[t]       = g * (e0 * einv) + (1.f - g) * w_prev[b * N_ + t];
    wgbuf[t + 512] = g * (e1 * einv) + (1.f - g) * w_prev[b * N_ + t + 512];
    __syncthreads();
    const float wt0 = s0 * wgbuf[(t - 1) & (N_ - 1)] + s1 * wgbuf[t] + s2 * wgbuf[(t + 1) & (N_ - 1)];
    const float wt1 = s0 * wgbuf[(t + 511) & (N_ - 1)] + s1 * wgbuf[t + 512] + s2 * wgbuf[(t + 513) & (N_ - 1)];
    const float wp0 = powf(wt0 + 1e-16f, y);
    const float wp1 = powf(wt1 + 1e-16f, y);
    v = wp0 + wp1;
    #pragma unroll
    for (int m = 1; m < 64; m <<= 1) v += __shfl_xor(v, m);
    __syncthreads();
    if (lane == 0) red[wid] = v;
    __syncthreads();
    float psum = 0.f;
    #pragma unroll
    for (int j = 0; j < 8; ++j) psum += red[j];
    const float pinv = 1.f / psum;
    const float wf0 = wp0 * pinv, wf1 = wp1 * pinv;
    zbuf[t] = wf0;       out_w[b * N_ + t] = wf0;
    zbuf[t + 512] = wf1; out_w[b * N_ + t + 512] = wf1;
    __syncthreads();

    // ---- pass 2: out_md[b,:] = sum_n w[n] * mem[b,n,:] (L2/L3-resident) ----
    float4 a0 = {0,0,0,0}, a1 = {0,0,0,0}, a2 = {0,0,0,0}, a3 = {0,0,0,0};
    #pragma unroll 4
    for (int i = 0; i < 16; ++i) {
        const float wv = zbuf[wid * 128 + i * 8 + rg];
        const float4* p = (const float4*)(rowbase + (size_t)i * 8 * M_);
        const float4 v0 = p[0], v1 = p[1], v2 = p[2], v3 = p[3];
        a0.x = fmaf(wv, v0.x, a0.x); a0.y = fmaf(wv, v0.y, a0.y);
        a0.z = fmaf(wv, v0.z, a0.z); a0.w = fmaf(wv, v0.w, a0.w);
        a1.x = fmaf(wv, v1.x, a1.x); a1.y = fmaf(wv, v1.y, a1.y);
        a1.z = fmaf(wv, v1.z, a1.z); a1.w = fmaf(wv, v1.w, a1.w);
        a2.x = fmaf(wv, v2.x, a2.x); a2.y = fmaf(wv, v2.y, a2.y);
        a2.z = fmaf(wv, v2.z, a2.z); a2.w = fmaf(wv, v2.w, a2.w);
        a3.x = fmaf(wv, v3.x, a3.x); a3.y = fmaf(wv, v3.y, a3.y);
        a3.z = fmaf(wv, v3.z, a3.z); a3.w = fmaf(wv, v3.w, a3.w);
    }
    // reduce across row-groups (lane bits 3,4,5)
    #pragma unroll
    for (int m = 8; m < 64; m <<= 1) {
        a0.x += __shfl_xor(a0.x, m); a0.y += __shfl_xor(a0.y, m);
        a0.z += __shfl_xor(a0.z, m); a0.w += __shfl_xor(a0.w, m);
        a1.x += __shfl_xor(a1.x, m); a1.y += __shfl_xor(a1.y, m);
        a1.z += __shfl_xor(a1.z, m); a1.w += __shfl_xor(a1.w, m);
        a2.x += __shfl_xor(a2.x, m); a2.y += __shfl_xor(a2.y, m);
        a2.z += __shfl_xor(a2.z, m); a2.w += __shfl_xor(a2.w, m);
        a3.x += __shfl_xor(a3.x, m); a3.y += __shfl_xor(a3.y, m);
        a3.z += __shfl_xor(a3.z, m); a3.w += __shfl_xor(a3.w, m);
    }
    if (rg == 0) {
        *(float4*)&accw[wid][c * 16 + 0]  = a0;
        *(float4*)&accw[wid][c * 16 + 4]  = a1;
        *(float4*)&accw[wid][c * 16 + 8]  = a2;
        *(float4*)&accw[wid][c * 16 + 12] = a3;
    }
    __syncthreads();
    if (t < M_) {
        float s = accw[0][t];
        #pragma unroll
        for (int j = 1; j < 8; ++j) s += accw[j][t];
        out_md[b * M_ + t] = s;
    }
}

extern "C" void kernel_launch(void* const* d_in, const int* in_sizes, int n_in,
                              void* d_out, int out_size, void* d_ws, size_t ws_size,
                              hipStream_t stream) {
    const float* emb    = (const float*)d_in[0];
    const float* w_prev = (const float*)d_in[1];
    const float* mem    = (const float*)d_in[2];
    const float* W      = (const float*)d_in[3];
    const float* bias   = (const float*)d_in[4];

    float* out_md = (float*)d_out;               // (512,128) memory_data
    float* out_w  = (float*)d_out + B_ * M_;     // (512,1024) w

    k_fused<<<B_, 512, 0, stream>>>(emb, W, bias, w_prev, mem, out_md, out_w);
}